// Round 1
// baseline (517.609 us; speedup 1.0000x reference)
//
#include <hip/hip_runtime.h>
#include <math.h>

// ---------------------------------------------------------------------------
// DeepFM on MI355X.
// Pipeline: [wtrans x3] -> [gather+FM] -> [GEMM1] -> [GEMM2] -> [GEMM3] -> [final]
// GEMMs: bf16 MFMA 16x16x32, 128x128 block tile, BK=32, global_load_lds(16B) staging.
// Workspace layout (bytes), total ~65.0 MB:
//   regionA @ 0        : h0 bf16 [16384 x 864] (28,311,552) ; reused for h2 bf16 [16384 x 512]
//   regionB @ 28311552 : h1 bf16 [16384 x 1024] (33,554,432); reused for h3 f32 [16384 x 256]
//   Wt0 @ 61865984 : bf16 [1024 x 864]
//   Wt1 @ 63635456 : bf16 [512 x 1024]
//   Wt2 @ 64684032 : bf16 [256 x 512]
//   lg  @ 64946176 : f32 [16384]  (linear+FM partial logit)
// ---------------------------------------------------------------------------

typedef __attribute__((ext_vector_type(8))) short shortx8;
typedef __attribute__((ext_vector_type(4))) float floatx4;

#define AS1 __attribute__((address_space(1)))
#define AS3 __attribute__((address_space(3)))

__device__ __forceinline__ void load_lds_16(const void* g, void* l) {
    __builtin_amdgcn_global_load_lds((AS1 void*)g, (AS3 void*)l, 16, 0, 0);
}

// round-to-nearest-even fp32 -> bf16 bits
__device__ __forceinline__ unsigned short f2bf(float x) {
    union { float f; unsigned int u; } v; v.f = x;
    unsigned int r = v.u + 0x7fffu + ((v.u >> 16) & 1u);
    return (unsigned short)(r >> 16);
}

// ---------------------------------------------------------------------------
// Weight transpose + cast: W [K,N] f32 row-major -> Wt [N,Kpad] bf16 row-major,
// zero-filled for k in [K, Kpad).
// block (32,8); grid (Kpad/32, N/32). N multiple of 32, Kpad multiple of 32.
// ---------------------------------------------------------------------------
__global__ void wtrans(const float* __restrict__ W, unsigned short* __restrict__ Wt,
                       int K, int N, int Kpad)
{
    __shared__ float tile[32][33];
    const int k0 = blockIdx.x * 32, n0 = blockIdx.y * 32;
    const int tx = threadIdx.x, ty = threadIdx.y;
#pragma unroll
    for (int i = 0; i < 32; i += 8) {
        int k = k0 + ty + i;
        tile[ty + i][tx] = (k < K) ? W[(size_t)k * N + (n0 + tx)] : 0.f;
    }
    __syncthreads();
#pragma unroll
    for (int i = 0; i < 32; i += 8) {
        int n = n0 + ty + i, kk = k0 + tx;
        Wt[(size_t)n * Kpad + kk] = f2bf(tile[tx][ty + i]);
    }
}

// ---------------------------------------------------------------------------
// Gather + FM + linear logit. One wave per batch row; 4 waves/block.
// Writes h0 row (832 emb bf16 + 13 dense bf16 + 19 zero pad) and
// lg[b] = linear_logit + fm_logit (exact fp32).
// ---------------------------------------------------------------------------
__global__ __launch_bounds__(256)
void gather_fm(const int* __restrict__ xs, const float* __restrict__ xd,
               const float* __restrict__ emb, const float* __restrict__ lint,
               unsigned short* __restrict__ h0, float* __restrict__ lg)
{
    const int lane = threadIdx.x & 63;
    const int wave = threadIdx.x >> 6;
    const int b = blockIdx.x * 4 + wave;

    int idx = 0; float linv = 0.f;
    if (lane < 26) {
        idx = xs[b * 26 + lane];
        linv = lint[(size_t)lane * 100000 + idx];
    }
    const int d = lane & 31;
    const int half = lane >> 5;
    float s = 0.f, sq = 0.f;
    unsigned short* hrow = h0 + (size_t)b * 864;
#pragma unroll
    for (int it = 0; it < 13; ++it) {
        int f = it * 2 + half;                 // all 26 fields, 2 per iter
        int fidx = __shfl(idx, f);
        float v = emb[((size_t)f * 100000 + (size_t)fidx) * 32 + d];
        s += v; sq += v * v;
        hrow[f * 32 + d] = f2bf(v);
    }
    // s per lane covers half the fields for its d; combine halves
    s += __shfl_xor(s, 32);
    // sum over 64 lanes: 0.25*s^2 counts each d twice -> 0.5*sum_d s^2;
    // sq counted once per (f,d); linv once per f.
    float t = 0.25f * s * s - 0.5f * sq + linv;
#pragma unroll
    for (int off = 32; off >= 1; off >>= 1) t += __shfl_xor(t, off);
    if (lane == 0) lg[b] = t;

    if (lane < 13) {
        hrow[832 + lane] = f2bf(xd[b * 13 + lane]);   // dense feats -> cols 832..844
    } else if (lane < 32) {
        hrow[832 + lane] = 0;                          // zero pad cols 845..863
    }
}

// ---------------------------------------------------------------------------
// GEMM: Y[M,N] = relu(X[M,K] @ W + bias), X bf16 row-major, Wt = W^T bf16 [N,K].
// 128x128 block tile, 4 waves each computing 64x64 as 4x4 MFMA 16x16x32 tiles.
// M%128==0, N%128==0, K%32==0 guaranteed by caller.
// ---------------------------------------------------------------------------
template <typename OUT_T>
__global__ __launch_bounds__(256)
void gemm_bias_relu(const unsigned short* __restrict__ X,
                    const unsigned short* __restrict__ Wt,
                    const float* __restrict__ bias,
                    OUT_T* __restrict__ Y,
                    int M, int N, int K)
{
    __shared__ alignas(16) unsigned short As[128 * 32];
    __shared__ alignas(16) unsigned short Bs[128 * 32];

    const int tid  = threadIdx.x;
    const int lane = tid & 63;
    const int wave = tid >> 6;
    const int bm = blockIdx.x * 128;
    const int bn = blockIdx.y * 128;
    const int wm = (wave & 1) * 64;
    const int wn = (wave >> 1) * 64;
    const int lrow  = lane & 15;   // C/D col, A/B row index within 16
    const int lquad = lane >> 4;   // k-offset quad: k = lquad*8 + j

    floatx4 acc[4][4];
    const floatx4 z4 = {0.f, 0.f, 0.f, 0.f};
#pragma unroll
    for (int i = 0; i < 4; ++i)
#pragma unroll
        for (int j = 0; j < 4; ++j) acc[i][j] = z4;

    // staging chunk indices: 512 x 16B chunks per tile; thread does c and c+256
    const int r0 = tid >> 2,        kp0 = (tid & 3) << 3;
    const int r1 = (tid + 256) >> 2, kp1 = ((tid + 256) & 3) << 3;

    for (int k0 = 0; k0 < K; k0 += 32) {
        load_lds_16(X  + (size_t)(bm + r0) * K + (k0 + kp0), As + (size_t)tid * 8);
        load_lds_16(Wt + (size_t)(bn + r0) * K + (k0 + kp0), Bs + (size_t)tid * 8);
        load_lds_16(X  + (size_t)(bm + r1) * K + (k0 + kp1), As + (size_t)(tid + 256) * 8);
        load_lds_16(Wt + (size_t)(bn + r1) * K + (k0 + kp1), Bs + (size_t)(tid + 256) * 8);
        __syncthreads();

        shortx8 a[4], b[4];
#pragma unroll
        for (int i = 0; i < 4; ++i)
            a[i] = *(const shortx8*)(As + (wm + i * 16 + lrow) * 32 + lquad * 8);
#pragma unroll
        for (int j = 0; j < 4; ++j)
            b[j] = *(const shortx8*)(Bs + (wn + j * 16 + lrow) * 32 + lquad * 8);
#pragma unroll
        for (int i = 0; i < 4; ++i)
#pragma unroll
            for (int j = 0; j < 4; ++j)
                acc[i][j] = __builtin_amdgcn_mfma_f32_16x16x32_bf16(a[i], b[j], acc[i][j], 0, 0, 0);
        __syncthreads();
    }

    // epilogue: C/D layout col=lane&15, row=(lane>>4)*4+r
#pragma unroll
    for (int i = 0; i < 4; ++i) {
        const int row = bm + wm + i * 16 + lquad * 4;
#pragma unroll
        for (int j = 0; j < 4; ++j) {
            const int col = bn + wn + j * 16 + lrow;
            const float bv = bias[col];
#pragma unroll
            for (int r = 0; r < 4; ++r) {
                float v = fmaxf(acc[i][j][r] + bv, 0.f);
                size_t off = (size_t)(row + r) * N + col;
                if (sizeof(OUT_T) == 4) ((float*)Y)[off] = v;
                else                    ((unsigned short*)Y)[off] = f2bf(v);
            }
        }
    }
}

// ---------------------------------------------------------------------------
// Final: out[b] = sigmoid(lg[b] + h3[b,:] . Wout + bout). One wave per row.
// ---------------------------------------------------------------------------
__global__ __launch_bounds__(256)
void final_out(const float* __restrict__ h3, const float* __restrict__ Wo,
               const float* __restrict__ bo, const float* __restrict__ lg,
               float* __restrict__ out)
{
    const int lane = threadIdx.x & 63;
    const int wave = threadIdx.x >> 6;
    const int b = blockIdx.x * 4 + wave;
    const float* row = h3 + (size_t)b * 256;
    float acc = 0.f;
#pragma unroll
    for (int q = 0; q < 4; ++q) acc += row[lane + q * 64] * Wo[lane + q * 64];
#pragma unroll
    for (int off = 32; off >= 1; off >>= 1) acc += __shfl_xor(acc, off);
    if (lane == 0) {
        float x = acc + bo[0] + lg[b];
        out[b] = 1.f / (1.f + expf(-x));
    }
}

extern "C" void kernel_launch(void* const* d_in, const int* in_sizes, int n_in,
                              void* d_out, int out_size, void* d_ws, size_t ws_size,
                              hipStream_t stream)
{
    const int*   xs = (const int*)d_in[0];
    const float* xd = (const float*)d_in[1];
    const float* em = (const float*)d_in[2];
    const float* li = (const float*)d_in[3];
    const float* W0 = (const float*)d_in[4];
    const float* b0 = (const float*)d_in[5];
    const float* W1 = (const float*)d_in[6];
    const float* b1 = (const float*)d_in[7];
    const float* W2 = (const float*)d_in[8];
    const float* b2 = (const float*)d_in[9];
    const float* Wo = (const float*)d_in[10];
    const float* bo = (const float*)d_in[11];
    float* out = (float*)d_out;

    char* ws = (char*)d_ws;
    unsigned short* h0  = (unsigned short*)(ws);             // regionA: 16384x864 bf16
    unsigned short* h1  = (unsigned short*)(ws + 28311552);  // regionB: 16384x1024 bf16
    unsigned short* h2  = (unsigned short*)(ws);             // regionA reuse: 16384x512 bf16
    float*          h3  = (float*)(ws + 28311552);           // regionB reuse: 16384x256 f32
    unsigned short* Wt0 = (unsigned short*)(ws + 61865984);  // 1024x864 bf16
    unsigned short* Wt1 = (unsigned short*)(ws + 63635456);  // 512x1024 bf16
    unsigned short* Wt2 = (unsigned short*)(ws + 64684032);  // 256x512 bf16
    float*          lg  = (float*)(ws + 64946176);           // 16384 f32

    dim3 tb(32, 8);
    wtrans<<<dim3(27, 32), tb, 0, stream>>>(W0, Wt0, 845, 1024, 864);
    wtrans<<<dim3(32, 16), tb, 0, stream>>>(W1, Wt1, 1024, 512, 1024);
    wtrans<<<dim3(16, 8),  tb, 0, stream>>>(W2, Wt2, 512, 256, 512);

    gather_fm<<<4096, 256, 0, stream>>>(xs, xd, em, li, h0, lg);

    gemm_bias_relu<unsigned short><<<dim3(128, 8), 256, 0, stream>>>(h0, Wt0, b0, h1, 16384, 1024, 864);
    gemm_bias_relu<unsigned short><<<dim3(128, 4), 256, 0, stream>>>(h1, Wt1, b1, h2, 16384, 512, 1024);
    gemm_bias_relu<float>         <<<dim3(128, 2), 256, 0, stream>>>(h2, Wt2, b2, h3, 16384, 256, 512);

    final_out<<<4096, 256, 0, stream>>>(h3, Wo, bo, lg, out);
}

// Round 2
// 499.237 us; speedup vs baseline: 1.0368x; 1.0368x over previous
//
#include <hip/hip_runtime.h>
#include <math.h>

// ---------------------------------------------------------------------------
// DeepFM on MI355X, round 2.
// Pipeline: [wtrans x3] -> [gather+FM] -> [GEMM1 128x256] -> [GEMM2 128x128]
//           -> [GEMM3 64x256 fused with Wout-dot + sigmoid]
// Workspace layout (bytes):
//   regionA @ 0        : h0 bf16 [16384 x 864] ; reused for h2 bf16 [16384 x 512]
//   regionB @ 28311552 : h1 bf16 [16384 x 1024]
//   Wt0 @ 61865984 : bf16 [1024 x 864]
//   Wt1 @ 63635456 : bf16 [512 x 1024]
//   Wt2 @ 64684032 : bf16 [256 x 512]
//   lg  @ 64946176 : f32 [16384]  (linear+FM partial logit)
// ---------------------------------------------------------------------------

typedef __attribute__((ext_vector_type(8))) short shortx8;
typedef __attribute__((ext_vector_type(4))) float floatx4;

#define AS1 __attribute__((address_space(1)))
#define AS3 __attribute__((address_space(3)))

__device__ __forceinline__ void load_lds_16(const void* g, void* l) {
    __builtin_amdgcn_global_load_lds((AS1 void*)g, (AS3 void*)l, 16, 0, 0);
}

// round-to-nearest-even fp32 -> bf16 bits
__device__ __forceinline__ unsigned short f2bf(float x) {
    union { float f; unsigned int u; } v; v.f = x;
    unsigned int r = v.u + 0x7fffu + ((v.u >> 16) & 1u);
    return (unsigned short)(r >> 16);
}

// ---------------------------------------------------------------------------
// Weight transpose + cast: W [K,N] f32 -> Wt [N,Kpad] bf16, zero pad K..Kpad.
// ---------------------------------------------------------------------------
__global__ void wtrans(const float* __restrict__ W, unsigned short* __restrict__ Wt,
                       int K, int N, int Kpad)
{
    __shared__ float tile[32][33];
    const int k0 = blockIdx.x * 32, n0 = blockIdx.y * 32;
    const int tx = threadIdx.x, ty = threadIdx.y;
#pragma unroll
    for (int i = 0; i < 32; i += 8) {
        int k = k0 + ty + i;
        tile[ty + i][tx] = (k < K) ? W[(size_t)k * N + (n0 + tx)] : 0.f;
    }
    __syncthreads();
#pragma unroll
    for (int i = 0; i < 32; i += 8) {
        int n = n0 + ty + i, kk = k0 + tx;
        Wt[(size_t)n * Kpad + kk] = f2bf(tile[tx][ty + i]);
    }
}

// ---------------------------------------------------------------------------
// Gather + FM + linear logit. One wave per batch row; 4 waves/block.
// ---------------------------------------------------------------------------
__global__ __launch_bounds__(256)
void gather_fm(const int* __restrict__ xs, const float* __restrict__ xd,
               const float* __restrict__ emb, const float* __restrict__ lint,
               unsigned short* __restrict__ h0, float* __restrict__ lg)
{
    const int lane = threadIdx.x & 63;
    const int wave = threadIdx.x >> 6;
    const int b = blockIdx.x * 4 + wave;

    int idx = 0; float linv = 0.f;
    if (lane < 26) {
        idx = xs[b * 26 + lane];
        linv = lint[(size_t)lane * 100000 + idx];
    }
    const int d = lane & 31;
    const int half = lane >> 5;
    float s = 0.f, sq = 0.f;
    unsigned short* hrow = h0 + (size_t)b * 864;
#pragma unroll
    for (int it = 0; it < 13; ++it) {
        int f = it * 2 + half;
        int fidx = __shfl(idx, f);
        float v = emb[((size_t)f * 100000 + (size_t)fidx) * 32 + d];
        s += v; sq += v * v;
        hrow[f * 32 + d] = f2bf(v);
    }
    s += __shfl_xor(s, 32);
    float t = 0.25f * s * s - 0.5f * sq + linv;
#pragma unroll
    for (int off = 32; off >= 1; off >>= 1) t += __shfl_xor(t, off);
    if (lane == 0) lg[b] = t;

    if (lane < 13) {
        hrow[832 + lane] = f2bf(xd[b * 13 + lane]);
    } else if (lane < 32) {
        hrow[832 + lane] = 0;
    }
}

// ---------------------------------------------------------------------------
// GEMM big-N: Y[M,N] = relu(X@W + bias) bf16. 128x256 block tile, 4 waves of
// 64x128 (4x8 MFMA 16x16x32). 2 blocks/CU via __launch_bounds__(256,2).
// ---------------------------------------------------------------------------
__global__ __launch_bounds__(256, 2)
void gemm_bign(const unsigned short* __restrict__ X,
               const unsigned short* __restrict__ Wt,
               const float* __restrict__ bias,
               unsigned short* __restrict__ Y,
               int M, int N, int K)
{
    __shared__ alignas(16) unsigned short As[128 * 32];
    __shared__ alignas(16) unsigned short Bs[256 * 32];

    const int tid  = threadIdx.x;
    const int lane = tid & 63;
    const int wave = tid >> 6;
    const int bm = blockIdx.x * 128;
    const int bn = blockIdx.y * 256;
    const int wm = (wave & 1) * 64;
    const int wn = (wave >> 1) * 128;
    const int lrow  = lane & 15;
    const int lquad = lane >> 4;

    floatx4 acc[4][8];
    const floatx4 z4 = {0.f, 0.f, 0.f, 0.f};
#pragma unroll
    for (int i = 0; i < 4; ++i)
#pragma unroll
        for (int j = 0; j < 8; ++j) acc[i][j] = z4;

    const int ar = tid >> 2, akp = (tid & 3) << 3;

    for (int k0 = 0; k0 < K; k0 += 32) {
        // A: 512 x 16B chunks (128 rows x 32 k)
        load_lds_16(X + (size_t)(bm + ar) * K + (k0 + akp), As + (size_t)tid * 8);
        load_lds_16(X + (size_t)(bm + ar + 64) * K + (k0 + akp), As + (size_t)(tid + 256) * 8);
        // B: 1024 x 16B chunks (256 rows x 32 k)
#pragma unroll
        for (int q = 0; q < 4; ++q) {
            int c = tid + q * 256;
            load_lds_16(Wt + (size_t)(bn + (c >> 2)) * K + (k0 + akp), Bs + (size_t)c * 8);
        }
        __syncthreads();

        shortx8 a[4];
#pragma unroll
        for (int i = 0; i < 4; ++i)
            a[i] = *(const shortx8*)(As + (wm + i * 16 + lrow) * 32 + lquad * 8);
#pragma unroll
        for (int j = 0; j < 8; ++j) {
            shortx8 b = *(const shortx8*)(Bs + (wn + j * 16 + lrow) * 32 + lquad * 8);
#pragma unroll
            for (int i = 0; i < 4; ++i)
                acc[i][j] = __builtin_amdgcn_mfma_f32_16x16x32_bf16(a[i], b, acc[i][j], 0, 0, 0);
        }
        __syncthreads();
    }

#pragma unroll
    for (int i = 0; i < 4; ++i) {
        const int row = bm + wm + i * 16 + lquad * 4;
#pragma unroll
        for (int j = 0; j < 8; ++j) {
            const int col = bn + wn + j * 16 + lrow;
            const float bv = bias[col];
#pragma unroll
            for (int r = 0; r < 4; ++r) {
                float v = fmaxf(acc[i][j][r] + bv, 0.f);
                Y[(size_t)(row + r) * N + col] = f2bf(v);
            }
        }
    }
}

// ---------------------------------------------------------------------------
// GEMM 128x128 (round-1 structure) for layer 2: h2 = relu(h1@W1 + b1), bf16.
// ---------------------------------------------------------------------------
__global__ __launch_bounds__(256)
void gemm_bias_relu(const unsigned short* __restrict__ X,
                    const unsigned short* __restrict__ Wt,
                    const float* __restrict__ bias,
                    unsigned short* __restrict__ Y,
                    int M, int N, int K)
{
    __shared__ alignas(16) unsigned short As[128 * 32];
    __shared__ alignas(16) unsigned short Bs[128 * 32];

    const int tid  = threadIdx.x;
    const int lane = tid & 63;
    const int wave = tid >> 6;
    const int bm = blockIdx.x * 128;
    const int bn = blockIdx.y * 128;
    const int wm = (wave & 1) * 64;
    const int wn = (wave >> 1) * 64;
    const int lrow  = lane & 15;
    const int lquad = lane >> 4;

    floatx4 acc[4][4];
    const floatx4 z4 = {0.f, 0.f, 0.f, 0.f};
#pragma unroll
    for (int i = 0; i < 4; ++i)
#pragma unroll
        for (int j = 0; j < 4; ++j) acc[i][j] = z4;

    const int r0 = tid >> 2, kp0 = (tid & 3) << 3;

    for (int k0 = 0; k0 < K; k0 += 32) {
        load_lds_16(X  + (size_t)(bm + r0) * K + (k0 + kp0), As + (size_t)tid * 8);
        load_lds_16(Wt + (size_t)(bn + r0) * K + (k0 + kp0), Bs + (size_t)tid * 8);
        load_lds_16(X  + (size_t)(bm + r0 + 64) * K + (k0 + kp0), As + (size_t)(tid + 256) * 8);
        load_lds_16(Wt + (size_t)(bn + r0 + 64) * K + (k0 + kp0), Bs + (size_t)(tid + 256) * 8);
        __syncthreads();

        shortx8 a[4], b[4];
#pragma unroll
        for (int i = 0; i < 4; ++i)
            a[i] = *(const shortx8*)(As + (wm + i * 16 + lrow) * 32 + lquad * 8);
#pragma unroll
        for (int j = 0; j < 4; ++j)
            b[j] = *(const shortx8*)(Bs + (wn + j * 16 + lrow) * 32 + lquad * 8);
#pragma unroll
        for (int i = 0; i < 4; ++i)
#pragma unroll
            for (int j = 0; j < 4; ++j)
                acc[i][j] = __builtin_amdgcn_mfma_f32_16x16x32_bf16(a[i], b[j], acc[i][j], 0, 0, 0);
        __syncthreads();
    }

#pragma unroll
    for (int i = 0; i < 4; ++i) {
        const int row = bm + wm + i * 16 + lquad * 4;
#pragma unroll
        for (int j = 0; j < 4; ++j) {
            const int col = bn + wn + j * 16 + lrow;
            const float bv = bias[col];
#pragma unroll
            for (int r = 0; r < 4; ++r) {
                float v = fmaxf(acc[i][j][r] + bv, 0.f);
                Y[(size_t)(row + r) * N + col] = f2bf(v);
            }
        }
    }
}

// ---------------------------------------------------------------------------
// GEMM3 fused with output head. Block: 64 rows x full N=256 (K=512).
// Each wave computes 64x64 (4x4 MFMA tiles), epilogue applies bias+ReLU,
// dots with Wout, reduces across lanes+waves, adds lg+bout, sigmoid -> out.
// h3 is never materialized.
// ---------------------------------------------------------------------------
__global__ __launch_bounds__(256)
void gemm3_final(const unsigned short* __restrict__ X,   // h2 [16384 x 512] bf16
                 const unsigned short* __restrict__ Wt,  // Wt2 [256 x 512] bf16
                 const float* __restrict__ bias,         // b2 [256]
                 const float* __restrict__ Wo,           // [256]
                 const float* __restrict__ bo,           // [1]
                 const float* __restrict__ lg,           // [16384]
                 float* __restrict__ out)                // [16384]
{
    const int K = 512;
    __shared__ alignas(16) unsigned short As[64 * 32];
    __shared__ alignas(16) unsigned short Bs[256 * 32];
    __shared__ float red[4][64];

    const int tid  = threadIdx.x;
    const int lane = tid & 63;
    const int wave = tid >> 6;
    const int bm = blockIdx.x * 64;
    const int wn = wave * 64;          // wave's 64-col strip
    const int lrow  = lane & 15;
    const int lquad = lane >> 4;

    floatx4 acc[4][4];
    const floatx4 z4 = {0.f, 0.f, 0.f, 0.f};
#pragma unroll
    for (int i = 0; i < 4; ++i)
#pragma unroll
        for (int j = 0; j < 4; ++j) acc[i][j] = z4;

    const int ar = tid >> 2, akp = (tid & 3) << 3;

    for (int k0 = 0; k0 < K; k0 += 32) {
        // A: 256 chunks (64 rows x 32 k)
        load_lds_16(X + (size_t)(bm + ar) * K + (k0 + akp), As + (size_t)tid * 8);
        // B: 1024 chunks (256 rows x 32 k)
#pragma unroll
        for (int q = 0; q < 4; ++q) {
            int c = tid + q * 256;
            load_lds_16(Wt + (size_t)(c >> 2) * K + (k0 + akp), Bs + (size_t)c * 8);
        }
        __syncthreads();

        shortx8 a[4], b[4];
#pragma unroll
        for (int i = 0; i < 4; ++i)
            a[i] = *(const shortx8*)(As + (i * 16 + lrow) * 32 + lquad * 8);
#pragma unroll
        for (int j = 0; j < 4; ++j)
            b[j] = *(const shortx8*)(Bs + (wn + j * 16 + lrow) * 32 + lquad * 8);
#pragma unroll
        for (int i = 0; i < 4; ++i)
#pragma unroll
            for (int j = 0; j < 4; ++j)
                acc[i][j] = __builtin_amdgcn_mfma_f32_16x16x32_bf16(a[i], b[j], acc[i][j], 0, 0, 0);
        __syncthreads();
    }

    // epilogue: per-lane cols wn + j*16 + lrow
    float bv[4], wv[4];
#pragma unroll
    for (int j = 0; j < 4; ++j) {
        int col = wn + j * 16 + lrow;
        bv[j] = bias[col];
        wv[j] = Wo[col];
    }
#pragma unroll
    for (int i = 0; i < 4; ++i) {
#pragma unroll
        for (int r = 0; r < 4; ++r) {
            float p = 0.f;
#pragma unroll
            for (int j = 0; j < 4; ++j) {
                float v = fmaxf(acc[i][j][r] + bv[j], 0.f);
                p += v * wv[j];
            }
            // reduce over the 16 lanes sharing lquad (cols of this strip)
            p += __shfl_xor(p, 1);
            p += __shfl_xor(p, 2);
            p += __shfl_xor(p, 4);
            p += __shfl_xor(p, 8);
            if (lrow == 0) red[wave][i * 16 + lquad * 4 + r] = p;
        }
    }
    __syncthreads();
    if (tid < 64) {
        float s = red[0][tid] + red[1][tid] + red[2][tid] + red[3][tid];
        float x = s + bo[0] + lg[bm + tid];
        out[bm + tid] = 1.f / (1.f + expf(-x));
    }
}

extern "C" void kernel_launch(void* const* d_in, const int* in_sizes, int n_in,
                              void* d_out, int out_size, void* d_ws, size_t ws_size,
                              hipStream_t stream)
{
    const int*   xs = (const int*)d_in[0];
    const float* xd = (const float*)d_in[1];
    const float* em = (const float*)d_in[2];
    const float* li = (const float*)d_in[3];
    const float* W0 = (const float*)d_in[4];
    const float* b0 = (const float*)d_in[5];
    const float* W1 = (const float*)d_in[6];
    const float* b1 = (const float*)d_in[7];
    const float* W2 = (const float*)d_in[8];
    const float* b2 = (const float*)d_in[9];
    const float* Wo = (const float*)d_in[10];
    const float* bo = (const float*)d_in[11];
    float* out = (float*)d_out;

    char* ws = (char*)d_ws;
    unsigned short* h0  = (unsigned short*)(ws);             // 16384x864 bf16
    unsigned short* h1  = (unsigned short*)(ws + 28311552);  // 16384x1024 bf16
    unsigned short* h2  = (unsigned short*)(ws);             // reuse: 16384x512 bf16
    unsigned short* Wt0 = (unsigned short*)(ws + 61865984);  // 1024x864 bf16
    unsigned short* Wt1 = (unsigned short*)(ws + 63635456);  // 512x1024 bf16
    unsigned short* Wt2 = (unsigned short*)(ws + 64684032);  // 256x512 bf16
    float*          lg  = (float*)(ws + 64946176);           // 16384 f32

    dim3 tb(32, 8);
    wtrans<<<dim3(27, 32), tb, 0, stream>>>(W0, Wt0, 845, 1024, 864);
    wtrans<<<dim3(32, 16), tb, 0, stream>>>(W1, Wt1, 1024, 512, 1024);
    wtrans<<<dim3(16, 8),  tb, 0, stream>>>(W2, Wt2, 512, 256, 512);

    gather_fm<<<4096, 256, 0, stream>>>(xs, xd, em, li, h0, lg);

    gemm_bign<<<dim3(128, 4), 256, 0, stream>>>(h0, Wt0, b0, h1, 16384, 1024, 864);
    gemm_bias_relu<<<dim3(128, 4), 256, 0, stream>>>(h1, Wt1, b1, h2, 16384, 512, 1024);
    gemm3_final<<<256, 256, 0, stream>>>(h2, Wt2, b2, Wo, bo, lg, out);
}

// Round 3
// 493.505 us; speedup vs baseline: 1.0488x; 1.0116x over previous
//
#include <hip/hip_runtime.h>
#include <math.h>

// ---------------------------------------------------------------------------
// DeepFM on MI355X, round 3.
// Pipeline: [prep: wtrans x3 + gather+FM, one launch] -> [GEMM1 128x256 BK64]
//           -> [GEMM2 128x256 BK64] -> [GEMM3 64x256 fused head]
// Workspace layout (bytes):
//   h0  @ 0        : bf16 [16384 x 896] (29,360,128); reused for h2 bf16 [16384 x 512]
//   h1  @ 29360128 : bf16 [16384 x 1024] (33,554,432)
//   Wt0 @ 62914560 : bf16 [1024 x 896]
//   Wt1 @ 64749568 : bf16 [512 x 1024]
//   Wt2 @ 65798144 : bf16 [256 x 512]
//   lg  @ 66060288 : f32 [16384]
// ---------------------------------------------------------------------------

typedef __attribute__((ext_vector_type(8))) short shortx8;
typedef __attribute__((ext_vector_type(4))) float floatx4;

#define AS1 __attribute__((address_space(1)))
#define AS3 __attribute__((address_space(3)))

__device__ __forceinline__ void load_lds_16(const void* g, void* l) {
    __builtin_amdgcn_global_load_lds((AS1 void*)g, (AS3 void*)l, 16, 0, 0);
}

__device__ __forceinline__ unsigned short f2bf(float x) {
    union { float f; unsigned int u; } v; v.f = x;
    unsigned int r = v.u + 0x7fffu + ((v.u >> 16) & 1u);
    return (unsigned short)(r >> 16);
}

// ---------------------------------------------------------------------------
// Prep kernel: blockIdx ranges dispatch to gather+FM or one of 3 wtrans tiles.
//   [0, 4096)            : gather+FM (wave per batch row)
//   [4096, 4992)         : wtrans W0 -> Wt0 [1024 x 896], grid 28 x 32
//   [4992, 5504)         : wtrans W1 -> Wt1 [512 x 1024], grid 32 x 16
//   [5504, 5632)         : wtrans W2 -> Wt2 [256 x 512],  grid 16 x 8
// ---------------------------------------------------------------------------
__device__ __forceinline__
void wtrans_tile(const float* __restrict__ W, unsigned short* __restrict__ Wt,
                 int K, int N, int Kpad, int bx, int by, int tid)
{
    __shared__ float tile[32][33];
    const int k0 = bx * 32, n0 = by * 32;
    const int tx = tid & 31, ty = tid >> 5;
#pragma unroll
    for (int i = 0; i < 32; i += 8) {
        int k = k0 + ty + i;
        tile[ty + i][tx] = (k < K) ? W[(size_t)k * N + (n0 + tx)] : 0.f;
    }
    __syncthreads();
#pragma unroll
    for (int i = 0; i < 32; i += 8) {
        int n = n0 + ty + i, kk = k0 + tx;
        Wt[(size_t)n * Kpad + kk] = f2bf(tile[tx][ty + i]);
    }
}

__global__ __launch_bounds__(256)
void prep(const int* __restrict__ xs, const float* __restrict__ xd,
          const float* __restrict__ emb, const float* __restrict__ lint,
          const float* __restrict__ W0, const float* __restrict__ W1,
          const float* __restrict__ W2,
          unsigned short* __restrict__ h0, float* __restrict__ lg,
          unsigned short* __restrict__ Wt0, unsigned short* __restrict__ Wt1,
          unsigned short* __restrict__ Wt2)
{
    const int bid = blockIdx.x;
    const int tid = threadIdx.x;

    if (bid >= 4096) {
        int t = bid - 4096;
        if (t < 896)       wtrans_tile(W0, Wt0, 845, 1024, 896, t % 28, t / 28, tid);
        else if (t < 1408) wtrans_tile(W1, Wt1, 1024, 512, 1024, (t - 896) % 32, (t - 896) / 32, tid);
        else               wtrans_tile(W2, Wt2, 512, 256, 512, (t - 1408) % 16, (t - 1408) / 16, tid);
        return;
    }

    const int lane = tid & 63;
    const int wave = tid >> 6;
    const int b = bid * 4 + wave;

    int idx = 0; float linv = 0.f;
    if (lane < 26) {
        idx = xs[b * 26 + lane];
        linv = lint[(size_t)lane * 100000 + idx];
    }
    const int d = lane & 31;
    const int half = lane >> 5;
    float s = 0.f, sq = 0.f;
    unsigned short* hrow = h0 + (size_t)b * 896;
#pragma unroll
    for (int it = 0; it < 13; ++it) {
        int f = it * 2 + half;
        int fidx = __shfl(idx, f);
        float v = emb[((size_t)f * 100000 + (size_t)fidx) * 32 + d];
        s += v; sq += v * v;
        hrow[f * 32 + d] = f2bf(v);
    }
    s += __shfl_xor(s, 32);
    float t = 0.25f * s * s - 0.5f * sq + linv;
#pragma unroll
    for (int off = 32; off >= 1; off >>= 1) t += __shfl_xor(t, off);
    if (lane == 0) lg[b] = t;

    // cols 832..844 dense, 845..895 zero: lanes 13..63 cover 845..895 exactly
    if (lane < 13) hrow[832 + lane] = f2bf(xd[b * 13 + lane]);
    else           hrow[832 + lane] = 0;
}

// ---------------------------------------------------------------------------
// GEMM big-N BK=64: Y[M,N] = relu(X@W + bias) bf16. 128x256 block tile,
// 4 waves of 64x128 (4x8 MFMA 16x16x32, 2 k-steps/iter). K % 64 == 0.
// LDS 48 KB; 2 blocks/CU (VGPR-bound).
// ---------------------------------------------------------------------------
__global__ __launch_bounds__(256, 2)
void gemm_bign(const unsigned short* __restrict__ X,
               const unsigned short* __restrict__ Wt,
               const float* __restrict__ bias,
               unsigned short* __restrict__ Y,
               int M, int N, int K)
{
    __shared__ alignas(16) unsigned short As[128 * 64];
    __shared__ alignas(16) unsigned short Bs[256 * 64];

    const int tid  = threadIdx.x;
    const int lane = tid & 63;
    const int wave = tid >> 6;
    const int bm = blockIdx.x * 128;
    const int bn = blockIdx.y * 256;
    const int wm = (wave & 1) * 64;
    const int wn = (wave >> 1) * 128;
    const int lrow  = lane & 15;
    const int lquad = lane >> 4;

    floatx4 acc[4][8];
    const floatx4 z4 = {0.f, 0.f, 0.f, 0.f};
#pragma unroll
    for (int i = 0; i < 4; ++i)
#pragma unroll
        for (int j = 0; j < 8; ++j) acc[i][j] = z4;

    for (int k0 = 0; k0 < K; k0 += 64) {
        // A: 128 rows x 64 k = 1024 x 16B chunks (8 chunks/row)
#pragma unroll
        for (int q = 0; q < 4; ++q) {
            int c = tid + q * 256;
            load_lds_16(X + (size_t)(bm + (c >> 3)) * K + (k0 + (c & 7) * 8),
                        As + (size_t)c * 8);
        }
        // B: 256 rows x 64 k = 2048 x 16B chunks
#pragma unroll
        for (int q = 0; q < 8; ++q) {
            int c = tid + q * 256;
            load_lds_16(Wt + (size_t)(bn + (c >> 3)) * K + (k0 + (c & 7) * 8),
                        Bs + (size_t)c * 8);
        }
        __syncthreads();

#pragma unroll
        for (int s = 0; s < 2; ++s) {
            shortx8 a[4];
#pragma unroll
            for (int i = 0; i < 4; ++i)
                a[i] = *(const shortx8*)(As + (wm + i * 16 + lrow) * 64 + s * 32 + lquad * 8);
#pragma unroll
            for (int j = 0; j < 8; ++j) {
                shortx8 b = *(const shortx8*)(Bs + (wn + j * 16 + lrow) * 64 + s * 32 + lquad * 8);
#pragma unroll
                for (int i = 0; i < 4; ++i)
                    acc[i][j] = __builtin_amdgcn_mfma_f32_16x16x32_bf16(a[i], b, acc[i][j], 0, 0, 0);
            }
        }
        __syncthreads();
    }

#pragma unroll
    for (int i = 0; i < 4; ++i) {
        const int row = bm + wm + i * 16 + lquad * 4;
#pragma unroll
        for (int j = 0; j < 8; ++j) {
            const int col = bn + wn + j * 16 + lrow;
            const float bv = bias[col];
#pragma unroll
            for (int r = 0; r < 4; ++r) {
                float v = fmaxf(acc[i][j][r] + bv, 0.f);
                Y[(size_t)(row + r) * N + col] = f2bf(v);
            }
        }
    }
}

// ---------------------------------------------------------------------------
// GEMM3 fused with output head. Block: 64 rows x full N=256 (K=512, BK=32).
// ---------------------------------------------------------------------------
__global__ __launch_bounds__(256)
void gemm3_final(const unsigned short* __restrict__ X,   // h2 [16384 x 512] bf16
                 const unsigned short* __restrict__ Wt,  // Wt2 [256 x 512] bf16
                 const float* __restrict__ bias,         // b2 [256]
                 const float* __restrict__ Wo,           // [256]
                 const float* __restrict__ bo,           // [1]
                 const float* __restrict__ lg,           // [16384]
                 float* __restrict__ out)                // [16384]
{
    const int K = 512;
    __shared__ alignas(16) unsigned short As[64 * 32];
    __shared__ alignas(16) unsigned short Bs[256 * 32];
    __shared__ float red[4][64];

    const int tid  = threadIdx.x;
    const int lane = tid & 63;
    const int wave = tid >> 6;
    const int bm = blockIdx.x * 64;
    const int wn = wave * 64;
    const int lrow  = lane & 15;
    const int lquad = lane >> 4;

    floatx4 acc[4][4];
    const floatx4 z4 = {0.f, 0.f, 0.f, 0.f};
#pragma unroll
    for (int i = 0; i < 4; ++i)
#pragma unroll
        for (int j = 0; j < 4; ++j) acc[i][j] = z4;

    const int ar = tid >> 2, akp = (tid & 3) << 3;

    for (int k0 = 0; k0 < K; k0 += 32) {
        load_lds_16(X + (size_t)(bm + ar) * K + (k0 + akp), As + (size_t)tid * 8);
#pragma unroll
        for (int q = 0; q < 4; ++q) {
            int c = tid + q * 256;
            load_lds_16(Wt + (size_t)(c >> 2) * K + (k0 + akp), Bs + (size_t)c * 8);
        }
        __syncthreads();

        shortx8 a[4], b[4];
#pragma unroll
        for (int i = 0; i < 4; ++i)
            a[i] = *(const shortx8*)(As + (i * 16 + lrow) * 32 + lquad * 8);
#pragma unroll
        for (int j = 0; j < 4; ++j)
            b[j] = *(const shortx8*)(Bs + (wn + j * 16 + lrow) * 32 + lquad * 8);
#pragma unroll
        for (int i = 0; i < 4; ++i)
#pragma unroll
            for (int j = 0; j < 4; ++j)
                acc[i][j] = __builtin_amdgcn_mfma_f32_16x16x32_bf16(a[i], b[j], acc[i][j], 0, 0, 0);
        __syncthreads();
    }

    float bv[4], wv[4];
#pragma unroll
    for (int j = 0; j < 4; ++j) {
        int col = wn + j * 16 + lrow;
        bv[j] = bias[col];
        wv[j] = Wo[col];
    }
#pragma unroll
    for (int i = 0; i < 4; ++i) {
#pragma unroll
        for (int r = 0; r < 4; ++r) {
            float p = 0.f;
#pragma unroll
            for (int j = 0; j < 4; ++j) {
                float v = fmaxf(acc[i][j][r] + bv[j], 0.f);
                p += v * wv[j];
            }
            p += __shfl_xor(p, 1);
            p += __shfl_xor(p, 2);
            p += __shfl_xor(p, 4);
            p += __shfl_xor(p, 8);
            if (lrow == 0) red[wave][i * 16 + lquad * 4 + r] = p;
        }
    }
    __syncthreads();
    if (tid < 64) {
        float s = red[0][tid] + red[1][tid] + red[2][tid] + red[3][tid];
        float x = s + bo[0] + lg[bm + tid];
        out[bm + tid] = 1.f / (1.f + expf(-x));
    }
}

extern "C" void kernel_launch(void* const* d_in, const int* in_sizes, int n_in,
                              void* d_out, int out_size, void* d_ws, size_t ws_size,
                              hipStream_t stream)
{
    const int*   xs = (const int*)d_in[0];
    const float* xd = (const float*)d_in[1];
    const float* em = (const float*)d_in[2];
    const float* li = (const float*)d_in[3];
    const float* W0 = (const float*)d_in[4];
    const float* b0 = (const float*)d_in[5];
    const float* W1 = (const float*)d_in[6];
    const float* b1 = (const float*)d_in[7];
    const float* W2 = (const float*)d_in[8];
    const float* b2 = (const float*)d_in[9];
    const float* Wo = (const float*)d_in[10];
    const float* bo = (const float*)d_in[11];
    float* out = (float*)d_out;

    char* ws = (char*)d_ws;
    unsigned short* h0  = (unsigned short*)(ws);             // 16384x896 bf16
    unsigned short* h1  = (unsigned short*)(ws + 29360128);  // 16384x1024 bf16
    unsigned short* h2  = (unsigned short*)(ws);             // reuse: 16384x512 bf16
    unsigned short* Wt0 = (unsigned short*)(ws + 62914560);  // 1024x896 bf16
    unsigned short* Wt1 = (unsigned short*)(ws + 64749568);  // 512x1024 bf16
    unsigned short* Wt2 = (unsigned short*)(ws + 65798144);  // 256x512 bf16
    float*          lg  = (float*)(ws + 66060288);           // 16384 f32

    prep<<<5632, 256, 0, stream>>>(xs, xd, em, li, W0, W1, W2, h0, lg, Wt0, Wt1, Wt2);

    gemm_bign<<<dim3(128, 4), 256, 0, stream>>>(h0, Wt0, b0, h1, 16384, 1024, 896);
    gemm_bign<<<dim3(128, 2), 256, 0, stream>>>(h1, Wt1, b1, h2, 16384, 512, 1024);
    gemm3_final<<<256, 256, 0, stream>>>(h2, Wt2, b2, Wo, bo, lg, out);
}